// Round 15
// baseline (497.709 us; speedup 1.0000x reference)
//
#include <hip/hip_runtime.h>
#include <hip/hip_bf16.h>

typedef _Float16 half8 __attribute__((ext_vector_type(8)));
typedef float f32x4 __attribute__((ext_vector_type(4)));

#define Bsz 32
#define Nseq 2048
#define Edim 1024
#define Hdim 1024

// async global->LDS, 16B per lane. LDS dest = wave-uniform base + lane*16;
// swizzled layouts via pre-swizzled per-lane GLOBAL source (rule #21).
__device__ __forceinline__ void gload_lds16(const void* g, void* l) {
    __builtin_amdgcn_global_load_lds(
        (const __attribute__((address_space(1))) unsigned int*)g,
        (__attribute__((address_space(3))) unsigned int*)l, 16, 0, 0);
}

// ---------------- kernel 1a: dw[b,h] = dec[b,:] @ w_d[:,h]  (f32) ------------
__global__ void k_dw(const float* __restrict__ dec, const float* __restrict__ w_d,
                     float* __restrict__ dw) {
    int b = blockIdx.x;
    int h = blockIdx.y * 256 + threadIdx.x;
    const float* dr = dec + b * 1024;
    float a0 = 0.f, a1 = 0.f, a2 = 0.f, a3 = 0.f;
    for (int d = 0; d < 1024; d += 4) {
        a0 += dr[d + 0] * w_d[(d + 0) * 1024 + h];
        a1 += dr[d + 1] * w_d[(d + 1) * 1024 + h];
        a2 += dr[d + 2] * w_d[(d + 2) * 1024 + h];
        a3 += dr[d + 3] * w_d[(d + 3) * 1024 + h];
    }
    dw[b * 1024 + h] = (a0 + a1) + (a2 + a3);
}

// ------- kernel 1b: split w_e (f32 [E][H]) into fp16 hi/lo, transposed [H][E] -
__global__ void k_split(const float* __restrict__ w_e,
                        _Float16* __restrict__ w_hiT, _Float16* __restrict__ w_loT) {
    __shared__ _Float16 th[32][33];
    __shared__ _Float16 tl[32][33];
    int e0 = blockIdx.x * 32, h0 = blockIdx.y * 32;
    int tx = threadIdx.x & 31, ty = threadIdx.x >> 5;
#pragma unroll
    for (int i = 0; i < 4; ++i) {
        int r = ty + i * 8;
        float x = w_e[(size_t)(e0 + r) * 1024 + h0 + tx];
        _Float16 h = (_Float16)x;
        th[r][tx] = h;
        tl[r][tx] = (_Float16)(x - (float)h);
    }
    __syncthreads();
#pragma unroll
    for (int i = 0; i < 4; ++i) {
        int r = ty + i * 8;
        w_hiT[(size_t)(h0 + r) * 1024 + e0 + tx] = th[tx][r];
        w_loT[(size_t)(h0 + r) * 1024 + e0 + tx] = tl[tx][r];
    }
}

// ---------------- kernel 2: scores[m] = sum_h w_out[h]*tanh((enc@w_e)[m,h]+dw[b,h])
// UNCHANGED from r14 (measured best family, 440-442us): fp16x3 split MFMA
// 16x16x32, 512 thr (8 waves 2x4), M_TILE=256, H_CHUNK=256, K_STEP=32,
// 4-phase counted-vmcnt schedule, stripe-XOR swizzle (conflicts 0.0),
// B via pre-swizzled global_load_lds, reg-staged A, XCD blockIdx swizzle,
// pass-ordered MFMA.
// Structure-class ceiling note: 7 variants measured in [440,530]; ~45% of the
// 199us fp16x3 MFMA floor. BK=64 (m201-class 62%) cannot fit: hi/lo doubles
// LDS -> 256KB needed > 160KB.
__global__ __launch_bounds__(512, 2)
void k_scores(const float* __restrict__ enc,
              const _Float16* __restrict__ w_hiT, const _Float16* __restrict__ w_loT,
              const float* __restrict__ dw, const float* __restrict__ w_out,
              float* __restrict__ scores) {
    extern __shared__ __align__(16) char smem[];
    float* scoreL = (float*)(smem + 131072);

    const int tid  = threadIdx.x;
    const int lane = tid & 63;
    const int wave = tid >> 6;
    const int wr = wave >> 2, wc = wave & 3;     // 2 x 4 wave grid
    const int bswz = ((blockIdx.x & 7) << 5) | (blockIdx.x >> 3);  // XCD swizzle
    const int m0 = bswz * 256;
    const int bb = m0 >> 11;
    const float* dwb = dw + bb * 1024;
    const int rb = lane & 15, ksl = lane >> 4;

    const int a_row = tid >> 2, a_ks = tid & 3;
    const float* aBase = enc + (size_t)(m0 + a_row) * 1024 + a_ks * 8;
    const int aWofs = (a_row >> 1) * 128 + (a_row & 1) * 64
                    + ((a_ks ^ ((a_row >> 1) & 3)) << 4);
    const int bRow0 = 2 * (tid >> 3) + ((tid >> 2) & 1);
    const int bD    = ((tid & 3) ^ ((tid >> 3) & 3)) << 4;
    const char* whiB = (const char*)w_hiT;
    const char* wloB = (const char*)w_loT;

    const int p2 = rb >> 1;
    const int swz = (ksl ^ (p2 & 3)) << 4;
    const int aRd = wr * 8192 + p2 * 128 + (rb & 1) * 64 + swz;  // + m*1024
    const int bRd = wc * 4096 + p2 * 128 + (rb & 1) * 64 + swz;  // + n*1024

    if (tid < 256) scoreL[tid] = 0.f;

    f32x4 acc[8][4];
#pragma unroll
    for (int m = 0; m < 8; ++m)
#pragma unroll
        for (int n = 0; n < 4; ++n) acc[m][n] = (f32x4){0.f, 0.f, 0.f, 0.f};

    float4 pa0, pa1, pa2, pa3;

#define A_LOAD(t) do { \
        const float* _p = aBase + (((t) & 31) << 5); \
        pa0 = ((const float4*)_p)[0]; \
        pa1 = ((const float4*)_p)[1]; \
        const float* _p2 = _p + 128 * 1024; \
        pa2 = ((const float4*)_p2)[0]; \
        pa3 = ((const float4*)_p2)[1]; \
    } while (0)
#define B_ISSUE_HI(t, buf) do { \
        const size_t _h = ((size_t)((t) >> 5) << 19) + (size_t)(((t) & 31)) * 64 + bD; \
        char* _b = smem + 65536 + (buf) * 32768; \
        gload_lds16(whiB + _h + (size_t)bRow0 * 2048,         _b + tid * 16); \
        gload_lds16(whiB + _h + (size_t)(bRow0 + 128) * 2048, _b + 8192 + tid * 16); \
    } while (0)
#define B_ISSUE_LO(t, buf) do { \
        const size_t _h = ((size_t)((t) >> 5) << 19) + (size_t)(((t) & 31)) * 64 + bD; \
        char* _b = smem + 65536 + (buf) * 32768 + 16384; \
        gload_lds16(wloB + _h + (size_t)bRow0 * 2048,         _b + tid * 16); \
        gload_lds16(wloB + _h + (size_t)(bRow0 + 128) * 2048, _b + 8192 + tid * 16); \
    } while (0)
#define A_STAGE(buf) do { \
        float _q[16] = {pa0.x, pa0.y, pa0.z, pa0.w, pa1.x, pa1.y, pa1.z, pa1.w, \
                        pa2.x, pa2.y, pa2.z, pa2.w, pa3.x, pa3.y, pa3.z, pa3.w}; \
        half8 _hi0, _lo0, _hi1, _lo1; \
        _Pragma("unroll") \
        for (int _j = 0; _j < 8; ++_j) { \
            _Float16 _h = (_Float16)_q[_j]; \
            _hi0[_j] = _h; \
            _lo0[_j] = (_Float16)(_q[_j] - (float)_h); \
            _Float16 _h2 = (_Float16)_q[_j + 8]; \
            _hi1[_j] = _h2; \
            _lo1[_j] = (_Float16)(_q[_j + 8] - (float)_h2); \
        } \
        char* _a = smem + (buf) * 32768; \
        *(half8*)(_a + aWofs)                 = _hi0; \
        *(half8*)(_a + 16384 + aWofs)         = _lo0; \
        *(half8*)(_a + 8192 + aWofs)          = _hi1; \
        *(half8*)(_a + 16384 + 8192 + aWofs)  = _lo1; \
    } while (0)
#define LOAD_A_FRAG(rh, rl, m) do { \
        rh = *(const half8*)(sa + aRd + (m) * 1024); \
        rl = *(const half8*)(sa + 16384 + aRd + (m) * 1024); \
    } while (0)
#define MFMA_PAIR(mb) do { \
        _Pragma("unroll") \
        for (int n = 0; n < 4; ++n) \
            acc[(mb)][n]   = __builtin_amdgcn_mfma_f32_16x16x32_f16(ah0, bh[n], acc[(mb)][n], 0, 0, 0); \
        _Pragma("unroll") \
        for (int n = 0; n < 4; ++n) \
            acc[(mb)+1][n] = __builtin_amdgcn_mfma_f32_16x16x32_f16(ah1, bh[n], acc[(mb)+1][n], 0, 0, 0); \
        _Pragma("unroll") \
        for (int n = 0; n < 4; ++n) \
            acc[(mb)][n]   = __builtin_amdgcn_mfma_f32_16x16x32_f16(ah0, bl[n], acc[(mb)][n], 0, 0, 0); \
        _Pragma("unroll") \
        for (int n = 0; n < 4; ++n) \
            acc[(mb)+1][n] = __builtin_amdgcn_mfma_f32_16x16x32_f16(ah1, bl[n], acc[(mb)+1][n], 0, 0, 0); \
        _Pragma("unroll") \
        for (int n = 0; n < 4; ++n) \
            acc[(mb)][n]   = __builtin_amdgcn_mfma_f32_16x16x32_f16(al0, bh[n], acc[(mb)][n], 0, 0, 0); \
        _Pragma("unroll") \
        for (int n = 0; n < 4; ++n) \
            acc[(mb)+1][n] = __builtin_amdgcn_mfma_f32_16x16x32_f16(al1, bh[n], acc[(mb)+1][n], 0, 0, 0); \
    } while (0)
#define WAITLG0 do { asm volatile("s_waitcnt lgkmcnt(0)" ::: "memory"); \
                     __builtin_amdgcn_sched_barrier(0); } while (0)

    A_LOAD(0);
    B_ISSUE_HI(0, 0);
    B_ISSUE_LO(0, 0);
    A_STAGE(0);
    A_LOAD(1);
    asm volatile("s_waitcnt vmcnt(0) lgkmcnt(0)" ::: "memory");
    __builtin_amdgcn_sched_barrier(0);
    __builtin_amdgcn_s_barrier();

    for (int t = 0; t < 128; ++t) {
        const int cur = t & 1;
        const char* sa = smem + cur * 32768;
        const char* sb = smem + 65536 + cur * 32768;
        half8 bh[4], bl[4];
        half8 ah0, al0, ah1, al1;

        // P0: 12 ds_read (A m0,m1 + all B) | gload B-hi(t+1)
        LOAD_A_FRAG(ah0, al0, 0);
        LOAD_A_FRAG(ah1, al1, 1);
#pragma unroll
        for (int n = 0; n < 4; ++n) {
            bh[n] = *(const half8*)(sb + bRd + n * 1024);
            bl[n] = *(const half8*)(sb + 16384 + bRd + n * 1024);
        }
        if (t < 127) B_ISSUE_HI(t + 1, cur ^ 1);
        asm volatile("s_waitcnt lgkmcnt(8)" ::: "memory");
        __builtin_amdgcn_sched_barrier(0);
        __builtin_amdgcn_s_barrier();
        WAITLG0;
        __builtin_amdgcn_s_setprio(1);
        MFMA_PAIR(0);
        __builtin_amdgcn_s_setprio(0);
        __builtin_amdgcn_s_barrier();

        // P1: 4 ds_read (A m2,m3) | gload B-lo(t+1)
        LOAD_A_FRAG(ah0, al0, 2);
        LOAD_A_FRAG(ah1, al1, 3);
        if (t < 127) B_ISSUE_LO(t + 1, cur ^ 1);
        __builtin_amdgcn_s_barrier();
        WAITLG0;
        __builtin_amdgcn_s_setprio(1);
        MFMA_PAIR(2);
        __builtin_amdgcn_s_setprio(0);
        __builtin_amdgcn_s_barrier();

        // P2: 4 ds_read (A m4,m5) | convert+ds_write A(t+1)
        LOAD_A_FRAG(ah0, al0, 4);
        LOAD_A_FRAG(ah1, al1, 5);
        if (t < 127) A_STAGE(cur ^ 1);
        __builtin_amdgcn_s_barrier();
        WAITLG0;
        __builtin_amdgcn_s_setprio(1);
        MFMA_PAIR(4);
        __builtin_amdgcn_s_setprio(0);
        __builtin_amdgcn_s_barrier();

        // P3: 4 ds_read (A m6,m7) | raw A loads(t+2) | vmcnt(4)
        LOAD_A_FRAG(ah0, al0, 6);
        LOAD_A_FRAG(ah1, al1, 7);
        if (t < 126) A_LOAD(t + 2);
        __builtin_amdgcn_s_barrier();
        if (t < 126) {
            asm volatile("s_waitcnt vmcnt(4) lgkmcnt(0)" ::: "memory");
        } else {
            asm volatile("s_waitcnt vmcnt(0) lgkmcnt(0)" ::: "memory");
        }
        __builtin_amdgcn_sched_barrier(0);
        __builtin_amdgcn_s_setprio(1);
        MFMA_PAIR(6);
        __builtin_amdgcn_s_setprio(0);

        if ((t & 31) == 31) {
            const int h0 = (t >> 5) << 8;
#pragma unroll
            for (int m = 0; m < 8; ++m) {
                float con[4] = {0.f, 0.f, 0.f, 0.f};
#pragma unroll
                for (int n = 0; n < 4; ++n) {
                    int h = h0 + wc * 64 + n * 16 + rb;
                    float dwv = dwb[h];
                    float wo  = w_out[h];
#pragma unroll
                    for (int r = 0; r < 4; ++r) {
                        float x = acc[m][n][r] + dwv;
                        float e = __expf(2.0f * fabsf(x));
                        float th = copysignf(1.0f - __fdividef(2.0f, e + 1.0f), x);
                        con[r] += th * wo;
                    }
                    acc[m][n] = (f32x4){0.f, 0.f, 0.f, 0.f};
                }
#pragma unroll
                for (int r = 0; r < 4; ++r) {
                    float v = con[r];
                    v += __shfl_xor(v, 1);
                    v += __shfl_xor(v, 2);
                    v += __shfl_xor(v, 4);
                    v += __shfl_xor(v, 8);
                    con[r] = v;
                }
                if (rb == 0) {
                    int rbase = wr * 128 + m * 16 + ksl * 4;
#pragma unroll
                    for (int r = 0; r < 4; ++r)
                        atomicAdd(&scoreL[rbase + r], con[r]);
                }
            }
        }
        __builtin_amdgcn_s_barrier();
    }

    __syncthreads();
    if (tid < 256) scores[m0 + tid] = scoreL[tid];
#undef A_LOAD
#undef B_ISSUE_HI
#undef B_ISSUE_LO
#undef A_STAGE
#undef LOAD_A_FRAG
#undef MFMA_PAIR
#undef WAITLG0
}

// -------- kernel 3 (fused): masked softmax + weighted enc sum per batch -----
// One block per batch b (256 thr). Phase 1: softmax over 2048 scores (probs
// kept in registers + survivor LDS append). Phase 2: attn[b,:] = sum over
// surviving rows (p>=1e-12; scores sigma~26 -> O(10) survivors) of p*enc.
// Block owns batch entirely -> plain float4 store: no memset, no atomics,
// one fewer launch than the split version.
__global__ void k_softmax_attn(const float* __restrict__ scores,
                               const int* __restrict__ mask,
                               const float* __restrict__ enc,
                               float* __restrict__ out_attn,
                               float* __restrict__ out_probs) {
    __shared__ float red[8];
    __shared__ float pv[2048];
    __shared__ int   pidx[2048];
    __shared__ int   cnt;
    int b = blockIdx.x, tid = threadIdx.x;
    if (tid == 0) cnt = 0;
    float v[8];
    float m = -INFINITY;
#pragma unroll
    for (int i = 0; i < 8; ++i) {
        int n = tid + i * 256;
        float s = scores[b * 2048 + n];
        s = (mask[b * 2048 + n] != 0) ? s : -INFINITY;
        v[i] = s;
        m = fmaxf(m, s);
    }
    for (int off = 32; off; off >>= 1) m = fmaxf(m, __shfl_xor(m, off));
    if ((tid & 63) == 0) red[tid >> 6] = m;
    __syncthreads();   // also covers cnt=0
    m = fmaxf(fmaxf(red[0], red[1]), fmaxf(red[2], red[3]));
    float sum = 0.f;
#pragma unroll
    for (int i = 0; i < 8; ++i) {
        v[i] = expf(v[i] - m);
        sum += v[i];
    }
    for (int off = 32; off; off >>= 1) sum += __shfl_xor(sum, off);
    if ((tid & 63) == 0) red[4 + (tid >> 6)] = sum;
    __syncthreads();
    sum = red[4] + red[5] + red[6] + red[7];
    float inv = 1.0f / sum;
#pragma unroll
    for (int i = 0; i < 8; ++i) {
        int n = tid + i * 256;
        float p = v[i] * inv;
        out_probs[b * 2048 + n] = p;
        if (p >= 1e-12f) {           // dropped mass <= 2e-9 -> attn err <= ~1e-8
            int slot = atomicAdd(&cnt, 1);
            pv[slot]   = p;
            pidx[slot] = n;
        }
    }
    __syncthreads();
    int nk = cnt;
    const float* eb = enc + (size_t)b * 2048 * 1024;
    float4 acc = {0.f, 0.f, 0.f, 0.f};
    for (int i = 0; i < nk; ++i) {
        float p = pv[i];
        float4 e4 = ((const float4*)(eb + (size_t)pidx[i] * 1024))[tid];
        acc.x += p * e4.x;
        acc.y += p * e4.y;
        acc.z += p * e4.z;
        acc.w += p * e4.w;
    }
    ((float4*)(out_attn + b * 1024))[tid] = acc;
}

extern "C" void kernel_launch(void* const* d_in, const int* in_sizes, int n_in,
                              void* d_out, int out_size, void* d_ws, size_t ws_size,
                              hipStream_t stream) {
    const float* enc   = (const float*)d_in[0];  // [32,2048,1024]
    const float* dec   = (const float*)d_in[1];  // [32,1024]
    const int*   mask  = (const int*)d_in[2];    // [32,2048] bool -> int32
    const float* w_e   = (const float*)d_in[3];  // [1024,1024]
    const float* w_d   = (const float*)d_in[4];  // [1024,1024]
    const float* w_out = (const float*)d_in[5];  // [1024]

    float* out_attn  = (float*)d_out;              // [32*1024]
    float* out_probs = out_attn + Bsz * Hdim;      // [32*2048]

    float* dw        = (float*)d_ws;               // 32*1024
    float* scores    = dw + Bsz * Hdim;            // 32*2048
    _Float16* w_hiT  = (_Float16*)(scores + Bsz * Nseq);  // [1024*1024]
    _Float16* w_loT  = w_hiT + Edim * Hdim;

    static const int kScoresLds = 132096;   // 128 KB bufs + 1 KB scoreL
    hipFuncSetAttribute((const void*)k_scores,
                        hipFuncAttributeMaxDynamicSharedMemorySize, kScoresLds);

    k_dw<<<dim3(32, 4), dim3(256), 0, stream>>>(dec, w_d, dw);
    k_split<<<dim3(32, 32), dim3(256), 0, stream>>>(w_e, w_hiT, w_loT);
    k_scores<<<dim3(256), dim3(512), kScoresLds, stream>>>(enc, w_hiT, w_loT, dw, w_out, scores);
    k_softmax_attn<<<dim3(32), dim3(256), 0, stream>>>(scores, mask, enc, out_attn, out_probs);
}

// Round 16
// 439.477 us; speedup vs baseline: 1.1325x; 1.1325x over previous
//
#include <hip/hip_runtime.h>
#include <hip/hip_bf16.h>

typedef _Float16 half8 __attribute__((ext_vector_type(8)));
typedef float f32x4 __attribute__((ext_vector_type(4)));

#define Bsz 32
#define Nseq 2048
#define Edim 1024
#define Hdim 1024

// async global->LDS, 16B per lane. LDS dest = wave-uniform base + lane*16;
// swizzled layouts via pre-swizzled per-lane GLOBAL source (rule #21).
__device__ __forceinline__ void gload_lds16(const void* g, void* l) {
    __builtin_amdgcn_global_load_lds(
        (const __attribute__((address_space(1))) unsigned int*)g,
        (__attribute__((address_space(3))) unsigned int*)l, 16, 0, 0);
}

// ---------------- kernel 1a: dw[b,h] = dec[b,:] @ w_d[:,h]  (f32) ------------
__global__ void k_dw(const float* __restrict__ dec, const float* __restrict__ w_d,
                     float* __restrict__ dw) {
    int b = blockIdx.x;
    int h = blockIdx.y * 256 + threadIdx.x;
    const float* dr = dec + b * 1024;
    float a0 = 0.f, a1 = 0.f, a2 = 0.f, a3 = 0.f;
    for (int d = 0; d < 1024; d += 4) {
        a0 += dr[d + 0] * w_d[(d + 0) * 1024 + h];
        a1 += dr[d + 1] * w_d[(d + 1) * 1024 + h];
        a2 += dr[d + 2] * w_d[(d + 2) * 1024 + h];
        a3 += dr[d + 3] * w_d[(d + 3) * 1024 + h];
    }
    dw[b * 1024 + h] = (a0 + a1) + (a2 + a3);
}

// ------- kernel 1b: split w_e (f32 [E][H]) into fp16 hi/lo, transposed [H][E] -
__global__ void k_split(const float* __restrict__ w_e,
                        _Float16* __restrict__ w_hiT, _Float16* __restrict__ w_loT) {
    __shared__ _Float16 th[32][33];
    __shared__ _Float16 tl[32][33];
    int e0 = blockIdx.x * 32, h0 = blockIdx.y * 32;
    int tx = threadIdx.x & 31, ty = threadIdx.x >> 5;
#pragma unroll
    for (int i = 0; i < 4; ++i) {
        int r = ty + i * 8;
        float x = w_e[(size_t)(e0 + r) * 1024 + h0 + tx];
        _Float16 h = (_Float16)x;
        th[r][tx] = h;
        tl[r][tx] = (_Float16)(x - (float)h);
    }
    __syncthreads();
#pragma unroll
    for (int i = 0; i < 4; ++i) {
        int r = ty + i * 8;
        w_hiT[(size_t)(h0 + r) * 1024 + e0 + tx] = th[tx][r];
        w_loT[(size_t)(h0 + r) * 1024 + e0 + tx] = tl[tx][r];
    }
}

// ---------------- kernel 2: scores[m] = sum_h w_out[h]*tanh((enc@w_e)[m,h]+dw[b,h])
// UNCHANGED (measured best family, 440-442us): fp16x3 split MFMA 16x16x32,
// 512 thr (8 waves 2x4), M_TILE=256, H_CHUNK=256, K_STEP=32, 4-phase
// counted-vmcnt schedule, stripe-XOR swizzle (conflicts 0.0), B via
// pre-swizzled global_load_lds, reg-staged A, XCD blockIdx swizzle,
// pass-ordered MFMA.
// Structure-class ceiling: ~45% of the 199us fp16x3 MFMA floor; 8 structural
// variants measured in [440,530]; BK=64 deep pipeline cannot fit (hi/lo
// doubles LDS -> >160KB).
__global__ __launch_bounds__(512, 2)
void k_scores(const float* __restrict__ enc,
              const _Float16* __restrict__ w_hiT, const _Float16* __restrict__ w_loT,
              const float* __restrict__ dw, const float* __restrict__ w_out,
              float* __restrict__ scores) {
    extern __shared__ __align__(16) char smem[];
    float* scoreL = (float*)(smem + 131072);

    const int tid  = threadIdx.x;
    const int lane = tid & 63;
    const int wave = tid >> 6;
    const int wr = wave >> 2, wc = wave & 3;     // 2 x 4 wave grid
    const int bswz = ((blockIdx.x & 7) << 5) | (blockIdx.x >> 3);  // XCD swizzle
    const int m0 = bswz * 256;
    const int bb = m0 >> 11;
    const float* dwb = dw + bb * 1024;
    const int rb = lane & 15, ksl = lane >> 4;

    const int a_row = tid >> 2, a_ks = tid & 3;
    const float* aBase = enc + (size_t)(m0 + a_row) * 1024 + a_ks * 8;
    const int aWofs = (a_row >> 1) * 128 + (a_row & 1) * 64
                    + ((a_ks ^ ((a_row >> 1) & 3)) << 4);
    const int bRow0 = 2 * (tid >> 3) + ((tid >> 2) & 1);
    const int bD    = ((tid & 3) ^ ((tid >> 3) & 3)) << 4;
    const char* whiB = (const char*)w_hiT;
    const char* wloB = (const char*)w_loT;

    const int p2 = rb >> 1;
    const int swz = (ksl ^ (p2 & 3)) << 4;
    const int aRd = wr * 8192 + p2 * 128 + (rb & 1) * 64 + swz;  // + m*1024
    const int bRd = wc * 4096 + p2 * 128 + (rb & 1) * 64 + swz;  // + n*1024

    if (tid < 256) scoreL[tid] = 0.f;

    f32x4 acc[8][4];
#pragma unroll
    for (int m = 0; m < 8; ++m)
#pragma unroll
        for (int n = 0; n < 4; ++n) acc[m][n] = (f32x4){0.f, 0.f, 0.f, 0.f};

    float4 pa0, pa1, pa2, pa3;

#define A_LOAD(t) do { \
        const float* _p = aBase + (((t) & 31) << 5); \
        pa0 = ((const float4*)_p)[0]; \
        pa1 = ((const float4*)_p)[1]; \
        const float* _p2 = _p + 128 * 1024; \
        pa2 = ((const float4*)_p2)[0]; \
        pa3 = ((const float4*)_p2)[1]; \
    } while (0)
#define B_ISSUE_HI(t, buf) do { \
        const size_t _h = ((size_t)((t) >> 5) << 19) + (size_t)(((t) & 31)) * 64 + bD; \
        char* _b = smem + 65536 + (buf) * 32768; \
        gload_lds16(whiB + _h + (size_t)bRow0 * 2048,         _b + tid * 16); \
        gload_lds16(whiB + _h + (size_t)(bRow0 + 128) * 2048, _b + 8192 + tid * 16); \
    } while (0)
#define B_ISSUE_LO(t, buf) do { \
        const size_t _h = ((size_t)((t) >> 5) << 19) + (size_t)(((t) & 31)) * 64 + bD; \
        char* _b = smem + 65536 + (buf) * 32768 + 16384; \
        gload_lds16(wloB + _h + (size_t)bRow0 * 2048,         _b + tid * 16); \
        gload_lds16(wloB + _h + (size_t)(bRow0 + 128) * 2048, _b + 8192 + tid * 16); \
    } while (0)
#define A_STAGE(buf) do { \
        float _q[16] = {pa0.x, pa0.y, pa0.z, pa0.w, pa1.x, pa1.y, pa1.z, pa1.w, \
                        pa2.x, pa2.y, pa2.z, pa2.w, pa3.x, pa3.y, pa3.z, pa3.w}; \
        half8 _hi0, _lo0, _hi1, _lo1; \
        _Pragma("unroll") \
        for (int _j = 0; _j < 8; ++_j) { \
            _Float16 _h = (_Float16)_q[_j]; \
            _hi0[_j] = _h; \
            _lo0[_j] = (_Float16)(_q[_j] - (float)_h); \
            _Float16 _h2 = (_Float16)_q[_j + 8]; \
            _hi1[_j] = _h2; \
            _lo1[_j] = (_Float16)(_q[_j + 8] - (float)_h2); \
        } \
        char* _a = smem + (buf) * 32768; \
        *(half8*)(_a + aWofs)                 = _hi0; \
        *(half8*)(_a + 16384 + aWofs)         = _lo0; \
        *(half8*)(_a + 8192 + aWofs)          = _hi1; \
        *(half8*)(_a + 16384 + 8192 + aWofs)  = _lo1; \
    } while (0)
#define LOAD_A_FRAG(rh, rl, m) do { \
        rh = *(const half8*)(sa + aRd + (m) * 1024); \
        rl = *(const half8*)(sa + 16384 + aRd + (m) * 1024); \
    } while (0)
#define MFMA_PAIR(mb) do { \
        _Pragma("unroll") \
        for (int n = 0; n < 4; ++n) \
            acc[(mb)][n]   = __builtin_amdgcn_mfma_f32_16x16x32_f16(ah0, bh[n], acc[(mb)][n], 0, 0, 0); \
        _Pragma("unroll") \
        for (int n = 0; n < 4; ++n) \
            acc[(mb)+1][n] = __builtin_amdgcn_mfma_f32_16x16x32_f16(ah1, bh[n], acc[(mb)+1][n], 0, 0, 0); \
        _Pragma("unroll") \
        for (int n = 0; n < 4; ++n) \
            acc[(mb)][n]   = __builtin_amdgcn_mfma_f32_16x16x32_f16(ah0, bl[n], acc[(mb)][n], 0, 0, 0); \
        _Pragma("unroll") \
        for (int n = 0; n < 4; ++n) \
            acc[(mb)+1][n] = __builtin_amdgcn_mfma_f32_16x16x32_f16(ah1, bl[n], acc[(mb)+1][n], 0, 0, 0); \
        _Pragma("unroll") \
        for (int n = 0; n < 4; ++n) \
            acc[(mb)][n]   = __builtin_amdgcn_mfma_f32_16x16x32_f16(al0, bh[n], acc[(mb)][n], 0, 0, 0); \
        _Pragma("unroll") \
        for (int n = 0; n < 4; ++n) \
            acc[(mb)+1][n] = __builtin_amdgcn_mfma_f32_16x16x32_f16(al1, bh[n], acc[(mb)+1][n], 0, 0, 0); \
    } while (0)
#define WAITLG0 do { asm volatile("s_waitcnt lgkmcnt(0)" ::: "memory"); \
                     __builtin_amdgcn_sched_barrier(0); } while (0)

    A_LOAD(0);
    B_ISSUE_HI(0, 0);
    B_ISSUE_LO(0, 0);
    A_STAGE(0);
    A_LOAD(1);
    asm volatile("s_waitcnt vmcnt(0) lgkmcnt(0)" ::: "memory");
    __builtin_amdgcn_sched_barrier(0);
    __builtin_amdgcn_s_barrier();

    for (int t = 0; t < 128; ++t) {
        const int cur = t & 1;
        const char* sa = smem + cur * 32768;
        const char* sb = smem + 65536 + cur * 32768;
        half8 bh[4], bl[4];
        half8 ah0, al0, ah1, al1;

        // P0: 12 ds_read (A m0,m1 + all B) | gload B-hi(t+1)
        LOAD_A_FRAG(ah0, al0, 0);
        LOAD_A_FRAG(ah1, al1, 1);
#pragma unroll
        for (int n = 0; n < 4; ++n) {
            bh[n] = *(const half8*)(sb + bRd + n * 1024);
            bl[n] = *(const half8*)(sb + 16384 + bRd + n * 1024);
        }
        if (t < 127) B_ISSUE_HI(t + 1, cur ^ 1);
        asm volatile("s_waitcnt lgkmcnt(8)" ::: "memory");
        __builtin_amdgcn_sched_barrier(0);
        __builtin_amdgcn_s_barrier();
        WAITLG0;
        __builtin_amdgcn_s_setprio(1);
        MFMA_PAIR(0);
        __builtin_amdgcn_s_setprio(0);
        __builtin_amdgcn_s_barrier();

        // P1: 4 ds_read (A m2,m3) | gload B-lo(t+1)
        LOAD_A_FRAG(ah0, al0, 2);
        LOAD_A_FRAG(ah1, al1, 3);
        if (t < 127) B_ISSUE_LO(t + 1, cur ^ 1);
        __builtin_amdgcn_s_barrier();
        WAITLG0;
        __builtin_amdgcn_s_setprio(1);
        MFMA_PAIR(2);
        __builtin_amdgcn_s_setprio(0);
        __builtin_amdgcn_s_barrier();

        // P2: 4 ds_read (A m4,m5) | convert+ds_write A(t+1)
        LOAD_A_FRAG(ah0, al0, 4);
        LOAD_A_FRAG(ah1, al1, 5);
        if (t < 127) A_STAGE(cur ^ 1);
        __builtin_amdgcn_s_barrier();
        WAITLG0;
        __builtin_amdgcn_s_setprio(1);
        MFMA_PAIR(4);
        __builtin_amdgcn_s_setprio(0);
        __builtin_amdgcn_s_barrier();

        // P3: 4 ds_read (A m6,m7) | raw A loads(t+2) | vmcnt(4)
        LOAD_A_FRAG(ah0, al0, 6);
        LOAD_A_FRAG(ah1, al1, 7);
        if (t < 126) A_LOAD(t + 2);
        __builtin_amdgcn_s_barrier();
        if (t < 126) {
            asm volatile("s_waitcnt vmcnt(4) lgkmcnt(0)" ::: "memory");
        } else {
            asm volatile("s_waitcnt vmcnt(0) lgkmcnt(0)" ::: "memory");
        }
        __builtin_amdgcn_sched_barrier(0);
        __builtin_amdgcn_s_setprio(1);
        MFMA_PAIR(6);
        __builtin_amdgcn_s_setprio(0);

        if ((t & 31) == 31) {
            const int h0 = (t >> 5) << 8;
#pragma unroll
            for (int m = 0; m < 8; ++m) {
                float con[4] = {0.f, 0.f, 0.f, 0.f};
#pragma unroll
                for (int n = 0; n < 4; ++n) {
                    int h = h0 + wc * 64 + n * 16 + rb;
                    float dwv = dwb[h];
                    float wo  = w_out[h];
#pragma unroll
                    for (int r = 0; r < 4; ++r) {
                        float x = acc[m][n][r] + dwv;
                        float e = __expf(2.0f * fabsf(x));
                        float th = copysignf(1.0f - __fdividef(2.0f, e + 1.0f), x);
                        con[r] += th * wo;
                    }
                    acc[m][n] = (f32x4){0.f, 0.f, 0.f, 0.f};
                }
#pragma unroll
                for (int r = 0; r < 4; ++r) {
                    float v = con[r];
                    v += __shfl_xor(v, 1);
                    v += __shfl_xor(v, 2);
                    v += __shfl_xor(v, 4);
                    v += __shfl_xor(v, 8);
                    con[r] = v;
                }
                if (rb == 0) {
                    int rbase = wr * 128 + m * 16 + ksl * 4;
#pragma unroll
                    for (int r = 0; r < 4; ++r)
                        atomicAdd(&scoreL[rbase + r], con[r]);
                }
            }
        }
        __builtin_amdgcn_s_barrier();
    }

    __syncthreads();
    if (tid < 256) scores[m0 + tid] = scoreL[tid];
#undef A_LOAD
#undef B_ISSUE_HI
#undef B_ISSUE_LO
#undef A_STAGE
#undef LOAD_A_FRAG
#undef MFMA_PAIR
#undef WAITLG0
}

// -------- kernel 3 (fused, PARALLEL): softmax + slice-owned weighted sum ----
// Grid (32 batches x 16 row-chunks), 256 thr. r15's 32-block fusion was
// latency-bound: ~200 survivors/batch (score sigma~14, cutoff ln(1e12)=27.6)
// x 4KB each on ONE block = ~50us. Here every block redoes the cheap full-row
// softmax reduction (16KB L2-hot reads, ~2us, parallel), then owns rows
// [c*128, c*128+128): writes its probs slice and accumulates its ~12
// survivors into out_attn via atomics (memset'd). = r14's work content,
// one fewer launch.
__global__ void k_softmax_attn(const float* __restrict__ scores,
                               const int* __restrict__ mask,
                               const float* __restrict__ enc,
                               float* __restrict__ out_attn,
                               float* __restrict__ out_probs) {
    __shared__ float red[8];
    __shared__ float pv[128];
    __shared__ int   pidx[128];
    __shared__ int   cnt;
    int b = blockIdx.x, c = blockIdx.y, tid = threadIdx.x;
    if (tid == 0) cnt = 0;
    // full-row max/sum reduction (redundant across c; trivially cheap)
    float v[8];
    float m = -INFINITY;
#pragma unroll
    for (int i = 0; i < 8; ++i) {
        int n = tid + i * 256;
        float s = scores[b * 2048 + n];
        s = (mask[b * 2048 + n] != 0) ? s : -INFINITY;
        v[i] = s;
        m = fmaxf(m, s);
    }
    for (int off = 32; off; off >>= 1) m = fmaxf(m, __shfl_xor(m, off));
    if ((tid & 63) == 0) red[tid >> 6] = m;
    __syncthreads();   // also covers cnt=0
    m = fmaxf(fmaxf(red[0], red[1]), fmaxf(red[2], red[3]));
    float sum = 0.f;
#pragma unroll
    for (int i = 0; i < 8; ++i) sum += expf(v[i] - m);
    for (int off = 32; off; off >>= 1) sum += __shfl_xor(sum, off);
    if ((tid & 63) == 0) red[4 + (tid >> 6)] = sum;
    __syncthreads();
    sum = red[4] + red[5] + red[6] + red[7];
    float inv = 1.0f / sum;
    // own slice: rows c*128 + t
    if (tid < 128) {
        int n = c * 128 + tid;
        float s = scores[b * 2048 + n];
        s = (mask[b * 2048 + n] != 0) ? s : -INFINITY;
        float p = expf(s - m) * inv;
        out_probs[b * 2048 + n] = p;
        if (p >= 1e-12f) {   // dropped mass <= 2e-9 -> attn err <= ~1e-8
            int slot = atomicAdd(&cnt, 1);
            pv[slot]   = p;
            pidx[slot] = n;
        }
    }
    __syncthreads();
    int nk = cnt;
    if (nk == 0) return;
    const float* eb = enc + (size_t)b * 2048 * 1024;
    float4 acc4 = {0.f, 0.f, 0.f, 0.f};
    for (int i = 0; i < nk; ++i) {
        float p = pv[i];
        float4 e4 = ((const float4*)(eb + (size_t)pidx[i] * 1024))[tid];
        acc4.x += p * e4.x;
        acc4.y += p * e4.y;
        acc4.z += p * e4.z;
        acc4.w += p * e4.w;
    }
    float* o = out_attn + b * 1024 + tid * 4;
    atomicAdd(o + 0, acc4.x);
    atomicAdd(o + 1, acc4.y);
    atomicAdd(o + 2, acc4.z);
    atomicAdd(o + 3, acc4.w);
}

extern "C" void kernel_launch(void* const* d_in, const int* in_sizes, int n_in,
                              void* d_out, int out_size, void* d_ws, size_t ws_size,
                              hipStream_t stream) {
    const float* enc   = (const float*)d_in[0];  // [32,2048,1024]
    const float* dec   = (const float*)d_in[1];  // [32,1024]
    const int*   mask  = (const int*)d_in[2];    // [32,2048] bool -> int32
    const float* w_e   = (const float*)d_in[3];  // [1024,1024]
    const float* w_d   = (const float*)d_in[4];  // [1024,1024]
    const float* w_out = (const float*)d_in[5];  // [1024]

    float* out_attn  = (float*)d_out;              // [32*1024]
    float* out_probs = out_attn + Bsz * Hdim;      // [32*2048]

    float* dw        = (float*)d_ws;               // 32*1024
    float* scores    = dw + Bsz * Hdim;            // 32*2048
    _Float16* w_hiT  = (_Float16*)(scores + Bsz * Nseq);  // [1024*1024]
    _Float16* w_loT  = w_hiT + Edim * Hdim;

    static const int kScoresLds = 132096;   // 128 KB bufs + 1 KB scoreL
    hipFuncSetAttribute((const void*)k_scores,
                        hipFuncAttributeMaxDynamicSharedMemorySize, kScoresLds);

    hipMemsetAsync(out_attn, 0, Bsz * Hdim * sizeof(float), stream);
    k_dw<<<dim3(32, 4), dim3(256), 0, stream>>>(dec, w_d, dw);
    k_split<<<dim3(32, 32), dim3(256), 0, stream>>>(w_e, w_hiT, w_loT);
    k_scores<<<dim3(256), dim3(512), kScoresLds, stream>>>(enc, w_hiT, w_loT, dw, w_out, scores);
    k_softmax_attn<<<dim3(32, 16), dim3(256), 0, stream>>>(scores, mask, enc, out_attn, out_probs);
}

// Round 17
// 433.219 us; speedup vs baseline: 1.1489x; 1.0144x over previous
//
#include <hip/hip_runtime.h>
#include <hip/hip_bf16.h>

typedef _Float16 half8 __attribute__((ext_vector_type(8)));
typedef float f32x4 __attribute__((ext_vector_type(4)));

#define Bsz 32
#define Nseq 2048
#define Edim 1024
#define Hdim 1024

// async global->LDS, 16B per lane. LDS dest = wave-uniform base + lane*16;
// swizzled layouts via pre-swizzled per-lane GLOBAL source (rule #21).
__device__ __forceinline__ void gload_lds16(const void* g, void* l) {
    __builtin_amdgcn_global_load_lds(
        (const __attribute__((address_space(1))) unsigned int*)g,
        (__attribute__((address_space(3))) unsigned int*)l, 16, 0, 0);
}

// ------ kernel 1 (merged): blk<1024 -> split w_e; blk>=1024 -> dw GEMV ------
// Merging the two independent prep kernels saves one launch + stream gap.
__global__ void k_prep(const float* __restrict__ w_e,
                       _Float16* __restrict__ w_hiT, _Float16* __restrict__ w_loT,
                       const float* __restrict__ dec, const float* __restrict__ w_d,
                       float* __restrict__ dw) {
    int blk = blockIdx.x;
    if (blk < 1024) {
        // ---- split w_e (f32 [E][H]) into fp16 hi/lo, transposed [H][E] ----
        __shared__ _Float16 th[32][33];
        __shared__ _Float16 tl[32][33];
        int e0 = (blk & 31) * 32, h0 = (blk >> 5) * 32;
        int tx = threadIdx.x & 31, ty = threadIdx.x >> 5;
#pragma unroll
        for (int i = 0; i < 4; ++i) {
            int r = ty + i * 8;
            float x = w_e[(size_t)(e0 + r) * 1024 + h0 + tx];
            _Float16 h = (_Float16)x;
            th[r][tx] = h;
            tl[r][tx] = (_Float16)(x - (float)h);
        }
        __syncthreads();
#pragma unroll
        for (int i = 0; i < 4; ++i) {
            int r = ty + i * 8;
            w_hiT[(size_t)(h0 + r) * 1024 + e0 + tx] = th[tx][r];
            w_loT[(size_t)(h0 + r) * 1024 + e0 + tx] = tl[tx][r];
        }
    } else {
        // ---- dw[b,h] = dec[b,:] @ w_d[:,h] (f32, 4 chains) ----
        int blk2 = blk - 1024;               // 0..127
        int b = blk2 >> 2;
        int h = (blk2 & 3) * 256 + threadIdx.x;
        const float* dr = dec + b * 1024;
        float a0 = 0.f, a1 = 0.f, a2 = 0.f, a3 = 0.f;
        for (int d = 0; d < 1024; d += 4) {
            a0 += dr[d + 0] * w_d[(d + 0) * 1024 + h];
            a1 += dr[d + 1] * w_d[(d + 1) * 1024 + h];
            a2 += dr[d + 2] * w_d[(d + 2) * 1024 + h];
            a3 += dr[d + 3] * w_d[(d + 3) * 1024 + h];
        }
        dw[b * 1024 + h] = (a0 + a1) + (a2 + a3);
    }
}

// ---------------- kernel 2: scores[m] = sum_h w_out[h]*tanh((enc@w_e)[m,h]+dw[b,h])
// FROZEN structure (measured best family, 439-442us): fp16x3 split MFMA
// 16x16x32, 512 thr (8 waves 2x4), M_TILE=256, H_CHUNK=256, K_STEP=32,
// 4-phase counted-vmcnt schedule, stripe-XOR swizzle (conflicts 0.0), B via
// pre-swizzled global_load_lds, reg-staged A, XCD blockIdx swizzle,
// pass-ordered MFMA. r16 micro: dropped the purposeless P0 pre-barrier
// lgkmcnt(8) stall (post-barrier lgkmcnt(0) covers correctness).
// Structure-class ceiling: ~45% of the 199us fp16x3 MFMA floor; 8 structural
// variants measured in [440,530]; BK=64 deep pipeline cannot fit (hi/lo
// doubles LDS -> >160KB).
__global__ __launch_bounds__(512, 2)
void k_scores(const float* __restrict__ enc,
              const _Float16* __restrict__ w_hiT, const _Float16* __restrict__ w_loT,
              const float* __restrict__ dw, const float* __restrict__ w_out,
              float* __restrict__ scores) {
    extern __shared__ __align__(16) char smem[];
    float* scoreL = (float*)(smem + 131072);

    const int tid  = threadIdx.x;
    const int lane = tid & 63;
    const int wave = tid >> 6;
    const int wr = wave >> 2, wc = wave & 3;     // 2 x 4 wave grid
    const int bswz = ((blockIdx.x & 7) << 5) | (blockIdx.x >> 3);  // XCD swizzle
    const int m0 = bswz * 256;
    const int bb = m0 >> 11;
    const float* dwb = dw + bb * 1024;
    const int rb = lane & 15, ksl = lane >> 4;

    const int a_row = tid >> 2, a_ks = tid & 3;
    const float* aBase = enc + (size_t)(m0 + a_row) * 1024 + a_ks * 8;
    const int aWofs = (a_row >> 1) * 128 + (a_row & 1) * 64
                    + ((a_ks ^ ((a_row >> 1) & 3)) << 4);
    const int bRow0 = 2 * (tid >> 3) + ((tid >> 2) & 1);
    const int bD    = ((tid & 3) ^ ((tid >> 3) & 3)) << 4;
    const char* whiB = (const char*)w_hiT;
    const char* wloB = (const char*)w_loT;

    const int p2 = rb >> 1;
    const int swz = (ksl ^ (p2 & 3)) << 4;
    const int aRd = wr * 8192 + p2 * 128 + (rb & 1) * 64 + swz;  // + m*1024
    const int bRd = wc * 4096 + p2 * 128 + (rb & 1) * 64 + swz;  // + n*1024

    if (tid < 256) scoreL[tid] = 0.f;

    f32x4 acc[8][4];
#pragma unroll
    for (int m = 0; m < 8; ++m)
#pragma unroll
        for (int n = 0; n < 4; ++n) acc[m][n] = (f32x4){0.f, 0.f, 0.f, 0.f};

    float4 pa0, pa1, pa2, pa3;

#define A_LOAD(t) do { \
        const float* _p = aBase + (((t) & 31) << 5); \
        pa0 = ((const float4*)_p)[0]; \
        pa1 = ((const float4*)_p)[1]; \
        const float* _p2 = _p + 128 * 1024; \
        pa2 = ((const float4*)_p2)[0]; \
        pa3 = ((const float4*)_p2)[1]; \
    } while (0)
#define B_ISSUE_HI(t, buf) do { \
        const size_t _h = ((size_t)((t) >> 5) << 19) + (size_t)(((t) & 31)) * 64 + bD; \
        char* _b = smem + 65536 + (buf) * 32768; \
        gload_lds16(whiB + _h + (size_t)bRow0 * 2048,         _b + tid * 16); \
        gload_lds16(whiB + _h + (size_t)(bRow0 + 128) * 2048, _b + 8192 + tid * 16); \
    } while (0)
#define B_ISSUE_LO(t, buf) do { \
        const size_t _h = ((size_t)((t) >> 5) << 19) + (size_t)(((t) & 31)) * 64 + bD; \
        char* _b = smem + 65536 + (buf) * 32768 + 16384; \
        gload_lds16(wloB + _h + (size_t)bRow0 * 2048,         _b + tid * 16); \
        gload_lds16(wloB + _h + (size_t)(bRow0 + 128) * 2048, _b + 8192 + tid * 16); \
    } while (0)
#define A_STAGE(buf) do { \
        float _q[16] = {pa0.x, pa0.y, pa0.z, pa0.w, pa1.x, pa1.y, pa1.z, pa1.w, \
                        pa2.x, pa2.y, pa2.z, pa2.w, pa3.x, pa3.y, pa3.z, pa3.w}; \
        half8 _hi0, _lo0, _hi1, _lo1; \
        _Pragma("unroll") \
        for (int _j = 0; _j < 8; ++_j) { \
            _Float16 _h = (_Float16)_q[_j]; \
            _hi0[_j] = _h; \
            _lo0[_j] = (_Float16)(_q[_j] - (float)_h); \
            _Float16 _h2 = (_Float16)_q[_j + 8]; \
            _hi1[_j] = _h2; \
            _lo1[_j] = (_Float16)(_q[_j + 8] - (float)_h2); \
        } \
        char* _a = smem + (buf) * 32768; \
        *(half8*)(_a + aWofs)                 = _hi0; \
        *(half8*)(_a + 16384 + aWofs)         = _lo0; \
        *(half8*)(_a + 8192 + aWofs)          = _hi1; \
        *(half8*)(_a + 16384 + 8192 + aWofs)  = _lo1; \
    } while (0)
#define LOAD_A_FRAG(rh, rl, m) do { \
        rh = *(const half8*)(sa + aRd + (m) * 1024); \
        rl = *(const half8*)(sa + 16384 + aRd + (m) * 1024); \
    } while (0)
#define MFMA_PAIR(mb) do { \
        _Pragma("unroll") \
        for (int n = 0; n < 4; ++n) \
            acc[(mb)][n]   = __builtin_amdgcn_mfma_f32_16x16x32_f16(ah0, bh[n], acc[(mb)][n], 0, 0, 0); \
        _Pragma("unroll") \
        for (int n = 0; n < 4; ++n) \
            acc[(mb)+1][n] = __builtin_amdgcn_mfma_f32_16x16x32_f16(ah1, bh[n], acc[(mb)+1][n], 0, 0, 0); \
        _Pragma("unroll") \
        for (int n = 0; n < 4; ++n) \
            acc[(mb)][n]   = __builtin_amdgcn_mfma_f32_16x16x32_f16(ah0, bl[n], acc[(mb)][n], 0, 0, 0); \
        _Pragma("unroll") \
        for (int n = 0; n < 4; ++n) \
            acc[(mb)+1][n] = __builtin_amdgcn_mfma_f32_16x16x32_f16(ah1, bl[n], acc[(mb)+1][n], 0, 0, 0); \
        _Pragma("unroll") \
        for (int n = 0; n < 4; ++n) \
            acc[(mb)][n]   = __builtin_amdgcn_mfma_f32_16x16x32_f16(al0, bh[n], acc[(mb)][n], 0, 0, 0); \
        _Pragma("unroll") \
        for (int n = 0; n < 4; ++n) \
            acc[(mb)+1][n] = __builtin_amdgcn_mfma_f32_16x16x32_f16(al1, bh[n], acc[(mb)+1][n], 0, 0, 0); \
    } while (0)
#define WAITLG0 do { asm volatile("s_waitcnt lgkmcnt(0)" ::: "memory"); \
                     __builtin_amdgcn_sched_barrier(0); } while (0)

    A_LOAD(0);
    B_ISSUE_HI(0, 0);
    B_ISSUE_LO(0, 0);
    A_STAGE(0);
    A_LOAD(1);
    asm volatile("s_waitcnt vmcnt(0) lgkmcnt(0)" ::: "memory");
    __builtin_amdgcn_sched_barrier(0);
    __builtin_amdgcn_s_barrier();

    for (int t = 0; t < 128; ++t) {
        const int cur = t & 1;
        const char* sa = smem + cur * 32768;
        const char* sb = smem + 65536 + cur * 32768;
        half8 bh[4], bl[4];
        half8 ah0, al0, ah1, al1;

        // P0: 12 ds_read (A m0,m1 + all B) | gload B-hi(t+1)
        LOAD_A_FRAG(ah0, al0, 0);
        LOAD_A_FRAG(ah1, al1, 1);
#pragma unroll
        for (int n = 0; n < 4; ++n) {
            bh[n] = *(const half8*)(sb + bRd + n * 1024);
            bl[n] = *(const half8*)(sb + 16384 + bRd + n * 1024);
        }
        if (t < 127) B_ISSUE_HI(t + 1, cur ^ 1);
        __builtin_amdgcn_s_barrier();
        WAITLG0;
        __builtin_amdgcn_s_setprio(1);
        MFMA_PAIR(0);
        __builtin_amdgcn_s_setprio(0);
        __builtin_amdgcn_s_barrier();

        // P1: 4 ds_read (A m2,m3) | gload B-lo(t+1)
        LOAD_A_FRAG(ah0, al0, 2);
        LOAD_A_FRAG(ah1, al1, 3);
        if (t < 127) B_ISSUE_LO(t + 1, cur ^ 1);
        __builtin_amdgcn_s_barrier();
        WAITLG0;
        __builtin_amdgcn_s_setprio(1);
        MFMA_PAIR(2);
        __builtin_amdgcn_s_setprio(0);
        __builtin_amdgcn_s_barrier();

        // P2: 4 ds_read (A m4,m5) | convert+ds_write A(t+1)
        LOAD_A_FRAG(ah0, al0, 4);
        LOAD_A_FRAG(ah1, al1, 5);
        if (t < 127) A_STAGE(cur ^ 1);
        __builtin_amdgcn_s_barrier();
        WAITLG0;
        __builtin_amdgcn_s_setprio(1);
        MFMA_PAIR(4);
        __builtin_amdgcn_s_setprio(0);
        __builtin_amdgcn_s_barrier();

        // P3: 4 ds_read (A m6,m7) | raw A loads(t+2) | vmcnt(4)
        LOAD_A_FRAG(ah0, al0, 6);
        LOAD_A_FRAG(ah1, al1, 7);
        if (t < 126) A_LOAD(t + 2);
        __builtin_amdgcn_s_barrier();
        if (t < 126) {
            asm volatile("s_waitcnt vmcnt(4) lgkmcnt(0)" ::: "memory");
        } else {
            asm volatile("s_waitcnt vmcnt(0) lgkmcnt(0)" ::: "memory");
        }
        __builtin_amdgcn_sched_barrier(0);
        __builtin_amdgcn_s_setprio(1);
        MFMA_PAIR(6);
        __builtin_amdgcn_s_setprio(0);

        if ((t & 31) == 31) {
            const int h0 = (t >> 5) << 8;
#pragma unroll
            for (int m = 0; m < 8; ++m) {
                float con[4] = {0.f, 0.f, 0.f, 0.f};
#pragma unroll
                for (int n = 0; n < 4; ++n) {
                    int h = h0 + wc * 64 + n * 16 + rb;
                    float dwv = dwb[h];
                    float wo  = w_out[h];
#pragma unroll
                    for (int r = 0; r < 4; ++r) {
                        float x = acc[m][n][r] + dwv;
                        float e = __expf(2.0f * fabsf(x));
                        float th = copysignf(1.0f - __fdividef(2.0f, e + 1.0f), x);
                        con[r] += th * wo;
                    }
                    acc[m][n] = (f32x4){0.f, 0.f, 0.f, 0.f};
                }
#pragma unroll
                for (int r = 0; r < 4; ++r) {
                    float v = con[r];
                    v += __shfl_xor(v, 1);
                    v += __shfl_xor(v, 2);
                    v += __shfl_xor(v, 4);
                    v += __shfl_xor(v, 8);
                    con[r] = v;
                }
                if (rb == 0) {
                    int rbase = wr * 128 + m * 16 + ksl * 4;
#pragma unroll
                    for (int r = 0; r < 4; ++r)
                        atomicAdd(&scoreL[rbase + r], con[r]);
                }
            }
        }
        __builtin_amdgcn_s_barrier();
    }

    __syncthreads();
    if (tid < 256) scores[m0 + tid] = scoreL[tid];
#undef A_LOAD
#undef B_ISSUE_HI
#undef B_ISSUE_LO
#undef A_STAGE
#undef LOAD_A_FRAG
#undef MFMA_PAIR
#undef WAITLG0
}

// -------- kernel 3 (fused, PARALLEL): softmax + slice-owned weighted sum ----
// Grid (32 batches x 16 row-chunks), 256 thr. Every block redoes the cheap
// full-row softmax reduction (16KB L2-hot, parallel), owns rows
// [c*128, c*128+128): writes its probs slice and accumulates its ~12
// survivors (p>=1e-12; ~200/batch total) into out_attn via atomics.
__global__ void k_softmax_attn(const float* __restrict__ scores,
                               const int* __restrict__ mask,
                               const float* __restrict__ enc,
                               float* __restrict__ out_attn,
                               float* __restrict__ out_probs) {
    __shared__ float red[8];
    __shared__ float pv[128];
    __shared__ int   pidx[128];
    __shared__ int   cnt;
    int b = blockIdx.x, c = blockIdx.y, tid = threadIdx.x;
    if (tid == 0) cnt = 0;
    float v[8];
    float m = -INFINITY;
#pragma unroll
    for (int i = 0; i < 8; ++i) {
        int n = tid + i * 256;
        float s = scores[b * 2048 + n];
        s = (mask[b * 2048 + n] != 0) ? s : -INFINITY;
        v[i] = s;
        m = fmaxf(m, s);
    }
    for (int off = 32; off; off >>= 1) m = fmaxf(m, __shfl_xor(m, off));
    if ((tid & 63) == 0) red[tid >> 6] = m;
    __syncthreads();   // also covers cnt=0
    m = fmaxf(fmaxf(red[0], red[1]), fmaxf(red[2], red[3]));
    float sum = 0.f;
#pragma unroll
    for (int i = 0; i < 8; ++i) sum += expf(v[i] - m);
    for (int off = 32; off; off >>= 1) sum += __shfl_xor(sum, off);
    if ((tid & 63) == 0) red[4 + (tid >> 6)] = sum;
    __syncthreads();
    sum = red[4] + red[5] + red[6] + red[7];
    float inv = 1.0f / sum;
    if (tid < 128) {
        int n = c * 128 + tid;
        float s = scores[b * 2048 + n];
        s = (mask[b * 2048 + n] != 0) ? s : -INFINITY;
        float p = expf(s - m) * inv;
        out_probs[b * 2048 + n] = p;
        if (p >= 1e-12f) {   // dropped mass <= 2e-9 -> attn err <= ~1e-8
            int slot = atomicAdd(&cnt, 1);
            pv[slot]   = p;
            pidx[slot] = n;
        }
    }
    __syncthreads();
    int nk = cnt;
    if (nk == 0) return;
    const float* eb = enc + (size_t)b * 2048 * 1024;
    float4 acc4 = {0.f, 0.f, 0.f, 0.f};
    for (int i = 0; i < nk; ++i) {
        float p = pv[i];
        float4 e4 = ((const float4*)(eb + (size_t)pidx[i] * 1024))[tid];
        acc4.x += p * e4.x;
        acc4.y += p * e4.y;
        acc4.z += p * e4.z;
        acc4.w += p * e4.w;
    }
    float* o = out_attn + b * 1024 + tid * 4;
    atomicAdd(o + 0, acc4.x);
    atomicAdd(o + 1, acc4.y);
    atomicAdd(o + 2, acc4.z);
    atomicAdd(o + 3, acc4.w);
}

extern "C" void kernel_launch(void* const* d_in, const int* in_sizes, int n_in,
                              void* d_out, int out_size, void* d_ws, size_t ws_size,
                              hipStream_t stream) {
    const float* enc   = (const float*)d_in[0];  // [32,2048,1024]
    const float* dec   = (const float*)d_in[1];  // [32,1024]
    const int*   mask  = (const int*)d_in[2];    // [32,2048] bool -> int32
    const float* w_e   = (const float*)d_in[3];  // [1024,1024]
    const float* w_d   = (const float*)d_in[4];  // [1024,1024]
    const float* w_out = (const float*)d_in[5];  // [1024]

    float* out_attn  = (float*)d_out;              // [32*1024]
    float* out_probs = out_attn + Bsz * Hdim;      // [32*2048]

    float* dw        = (float*)d_ws;               // 32*1024
    float* scores    = dw + Bsz * Hdim;            // 32*2048
    _Float16* w_hiT  = (_Float16*)(scores + Bsz * Nseq);  // [1024*1024]
    _Float16* w_loT  = w_hiT + Edim * Hdim;

    static const int kScoresLds = 132096;   // 128 KB bufs + 1 KB scoreL
    hipFuncSetAttribute((const void*)k_scores,
                        hipFuncAttributeMaxDynamicSharedMemorySize, kScoresLds);

    hipMemsetAsync(out_attn, 0, Bsz * Hdim * sizeof(float), stream);
    k_prep<<<dim3(1152), dim3(256), 0, stream>>>(w_e, w_hiT, w_loT, dec, w_d, dw);
    k_scores<<<dim3(256), dim3(512), kScoresLds, stream>>>(enc, w_hiT, w_loT, dw, w_out, scores);
    k_softmax_attn<<<dim3(32, 16), dim3(256), 0, stream>>>(scores, mask, enc, out_attn, out_probs);
}